// Round 1
// baseline (185.130 us; speedup 1.0000x reference)
//
#include <hip/hip_runtime.h>
#include <hip/hip_bf16.h>
#include <math.h>

#define EPS 1e-6f
#define TAU 1.0f

__device__ __forceinline__ void sigma_comps(float w, float h, float r,
                                            float& s11, float& s12, float& s22) {
    w = fminf(fmaxf(w, 1e-7f), 1e7f);
    h = fminf(fmaxf(h, 1e-7f), 1e7f);
    float a = 0.25f * w * w;
    float b = 0.25f * h * h;
    float s, c;
    __sincosf(r, &s, &c);
    float cc = c * c, ss = s * s, sc = s * c;
    s11 = a * cc + b * ss;
    s12 = (a - b) * sc;
    s22 = a * ss + b * cc;
}

__global__ void __launch_bounds__(256) gd_loss_kernel(
        const float* __restrict__ pred,
        const float* __restrict__ tgt,
        float* __restrict__ out, int n) {
    int i = blockIdx.x * blockDim.x + threadIdx.x;
    if (i >= n) return;

    const float* p = pred + (size_t)i * 5;
    const float* t = tgt  + (size_t)i * 5;

    float px = p[0], py = p[1], pw = p[2], ph = p[3], pr = p[4];
    float tx = t[0], ty = t[1], tw = t[2], th = t[3], tr = t[4];

    float p11, p12, p22, t11, t12, t22;
    sigma_comps(pw, ph, pr, p11, p12, p22);
    sigma_comps(tw, th, tr, t11, t12, t22);

    float det_p = p11 * p22 - p12 * p12;
    float det_t = t11 * t22 - t12 * t12;

    float dx = px - tx;
    float dy = py - ty;

    float inv_det_t = __frcp_rn(det_t);
    float term1 = (t22 * dx * dx - 2.0f * t12 * dx * dy + t11 * dy * dy) * inv_det_t;
    float trace_term = (t22 * p11 - 2.0f * t12 * p12 + t11 * p22) * inv_det_t;
    float term2 = trace_term + __logf(det_t) - __logf(det_p);

    float dis = term1 + term2 - 2.0f;
    float kl = fmaxf(dis, EPS);
    float loss = 1.0f - 1.0f / (TAU + sqrtf(kl));

    out[i] = loss;
}

extern "C" void kernel_launch(void* const* d_in, const int* in_sizes, int n_in,
                              void* d_out, int out_size, void* d_ws, size_t ws_size,
                              hipStream_t stream) {
    const float* pred = (const float*)d_in[0];
    const float* tgt  = (const float*)d_in[1];
    float* out = (float*)d_out;
    int n = out_size;  // N boxes, one loss per box

    int block = 256;
    int grid = (n + block - 1) / block;
    gd_loss_kernel<<<grid, block, 0, stream>>>(pred, tgt, out, n);
}